// Round 1
// baseline (553.979 us; speedup 1.0000x reference)
//
#include <hip/hip_runtime.h>
#include <math.h>

// Problem constants (match reference)
#define BATCH 512
#define M 128
#define D 512
#define NITER 400
#define PITER 30

#define GS_STRIDE 132   // G row stride in floats (128+4, 16B-aligned rows)
#define TILE_STRIDE 22  // ctr-chunk tile row stride (breaks bank conflicts, 8B aligned)
#define DC 16           // D-chunk size
#define NCHUNK (D / DC)

__launch_bounds__(256, 2)
__global__ void nnls_cone_kernel(const float* __restrict__ pred,
                                 const float* __restrict__ ctr,
                                 float* __restrict__ out)
{
    // LDS: G (aliased with the staging tile: tile only needs 128*22=2816 floats,
    // G written only after all chunks are consumed) + small vectors.
    __shared__ __align__(16) float gs[M * GS_STRIDE];   // 67584 B
    __shared__ __align__(16) float part[4 * M];         // per-wave matvec partials
    __shared__ __align__(16) float y_s[M];
    __shared__ __align__(16) float lam_s[M];
    __shared__ __align__(16) float b_s[M];
    __shared__ float rsum[M];                           // row |.| sums -> mask
    __shared__ float pchunk[DC];
    __shared__ float wred[4];

    const int tid = threadIdx.x;
    const int blk = blockIdx.x;
    const int w = tid >> 6;     // wave id 0..3 (column chunk of 32)
    const int l = tid & 63;     // lane -> rows l and l+64
    const int ti = tid >> 4;    // 0..15, A-row class (rows ti+16i)
    const int tj = tid & 15;    // 0..15, B-row class (rows tj+16j)

    const float* predRow = pred + (size_t)blk * D;
    const float* ctrBase = ctr + (size_t)blk * M * D;

    // ---- block-wide sum reduction (all 256 threads must call) ----
    auto blockReduce = [&](float v) -> float {
        #pragma unroll
        for (int off = 32; off > 0; off >>= 1)
            v += __shfl_down(v, off, 64);
        if (l == 0) wred[w] = v;
        __syncthreads();
        float s = wred[0] + wred[1] + wred[2] + wred[3];
        __syncthreads();
        return s;
    };

    // ---- ||p||^2 (p = -pred row; norm identical) ----
    float pv0 = predRow[tid];
    float pv1 = predRow[tid + 256];
    float pn2 = blockReduce(pv0 * pv0 + pv1 * pv1);

    if (tid < M) { b_s[tid] = 0.0f; rsum[tid] = 0.0f; }
    __syncthreads();

    // ---- Phase 1: G = C C^T into registers (8x8 tile per thread), b, rowsums ----
    float acc[8][8];
    #pragma unroll
    for (int i = 0; i < 8; ++i)
        #pragma unroll
        for (int j = 0; j < 8; ++j)
            acc[i][j] = 0.0f;

    const int m  = tid >> 1;        // staged row
    const int kk = (tid & 1) * 8;   // staged k offset within chunk
    float* tile = gs;               // alias into G region

    for (int kc = 0; kc < NCHUNK; ++kc) {
        const int k0 = kc * DC;
        const float* src = ctrBase + (size_t)m * D + k0 + kk;
        float4 f0 = *(const float4*)(src);
        float4 f1 = *(const float4*)(src + 4);
        if (tid < DC) pchunk[tid] = predRow[k0 + tid];

        float* tdst = tile + m * TILE_STRIDE + kk;
        *(float2*)(tdst + 0) = make_float2(f0.x, f0.y);
        *(float2*)(tdst + 2) = make_float2(f0.z, f0.w);
        *(float2*)(tdst + 4) = make_float2(f1.x, f1.y);
        *(float2*)(tdst + 6) = make_float2(f1.z, f1.w);
        __syncthreads();

        // row abs-sum and b = C*pred partials (sign flipped at the end)
        float rp = fabsf(f0.x) + fabsf(f0.y) + fabsf(f0.z) + fabsf(f0.w)
                 + fabsf(f1.x) + fabsf(f1.y) + fabsf(f1.z) + fabsf(f1.w);
        float bp = f0.x * pchunk[kk + 0] + f0.y * pchunk[kk + 1]
                 + f0.z * pchunk[kk + 2] + f0.w * pchunk[kk + 3]
                 + f1.x * pchunk[kk + 4] + f1.y * pchunk[kk + 5]
                 + f1.z * pchunk[kk + 6] + f1.w * pchunk[kk + 7];
        rp += __shfl_xor(rp, 1, 64);
        bp += __shfl_xor(bp, 1, 64);
        if ((tid & 1) == 0) { rsum[m] += rp; b_s[m] += bp; }

        // 8x8 outer-product accumulation over this chunk
        #pragma unroll
        for (int k = 0; k < DC; k += 2) {
            float2 a2[8], b2[8];
            #pragma unroll
            for (int i = 0; i < 8; ++i)
                a2[i] = *(const float2*)(tile + (ti + 16 * i) * TILE_STRIDE + k);
            #pragma unroll
            for (int j = 0; j < 8; ++j)
                b2[j] = *(const float2*)(tile + (tj + 16 * j) * TILE_STRIDE + k);
            #pragma unroll
            for (int i = 0; i < 8; ++i)
                #pragma unroll
                for (int j = 0; j < 8; ++j)
                    acc[i][j] += a2[i].x * b2[j].x + a2[i].y * b2[j].y;
        }
        __syncthreads();
    }

    // ---- mask + finalize b (b = C_masked * (-pred)) ----
    if (tid < M) {
        bool ok = rsum[tid] > 1e-7f;
        rsum[tid] = ok ? 1.0f : 0.0f;     // rsum becomes the mask
        b_s[tid] = ok ? -b_s[tid] : 0.0f;
    }
    __syncthreads();

    // ---- write masked G to LDS (tile region is dead now) ----
    #pragma unroll
    for (int i = 0; i < 8; ++i) {
        const int rA = ti + 16 * i;
        const float mi = rsum[rA];
        #pragma unroll
        for (int j = 0; j < 8; ++j) {
            const int rB = tj + 16 * j;
            gs[rA * GS_STRIDE + rB] = acc[i][j] * mi * rsum[rB];
        }
    }
    __syncthreads();

    // ---- load G into FISTA register layout: rows l & l+64, cols [32w,32w+32) ----
    float Ga[32], Gb[32];
    {
        const float4* pa4 = (const float4*)(gs + l * GS_STRIDE + (w << 5));
        const float4* pb4 = (const float4*)(gs + (l + 64) * GS_STRIDE + (w << 5));
        #pragma unroll
        for (int q = 0; q < 8; ++q) {
            float4 xa = pa4[q];
            Ga[4 * q + 0] = xa.x; Ga[4 * q + 1] = xa.y;
            Ga[4 * q + 2] = xa.z; Ga[4 * q + 3] = xa.w;
            float4 xb = pb4[q];
            Gb[4 * q + 0] = xb.x; Gb[4 * q + 1] = xb.y;
            Gb[4 * q + 2] = xb.z; Gb[4 * q + 3] = xb.w;
        }
    }

    // partial matvec: this wave's 32-column slice of G * vec for rows l, l+64
    auto matvecPart = [&](const float* vec, float& pa, float& pb) {
        const float4* vp = (const float4*)(vec + (w << 5));
        pa = 0.0f; pb = 0.0f;
        #pragma unroll
        for (int q = 0; q < 8; ++q) {
            float4 vv = vp[q];
            pa += Ga[4 * q + 0] * vv.x + Ga[4 * q + 1] * vv.y
                + Ga[4 * q + 2] * vv.z + Ga[4 * q + 3] * vv.w;
            pb += Gb[4 * q + 0] * vv.x + Gb[4 * q + 1] * vv.y
                + Gb[4 * q + 2] * vv.z + Gb[4 * q + 3] * vv.w;
        }
    };

    // ---- Phase 2: power iteration for L = ||G v|| ----
    if (tid < M) y_s[tid] = 1.0f;
    __syncthreads();
    for (int it = 0; it < PITER; ++it) {
        float pa, pb;
        matvecPart(y_s, pa, pb);
        part[w * 128 + l] = pa;
        part[w * 128 + 64 + l] = pb;
        __syncthreads();
        float u = 0.0f;
        if (tid < M)
            u = part[tid] + part[128 + tid] + part[256 + tid] + part[384 + tid];
        float ns = blockReduce(tid < M ? u * u : 0.0f);
        float nrm = sqrtf(ns);
        if (tid < M) y_s[tid] = u / (nrm + 1e-12f);
        __syncthreads();
    }
    float step;
    {
        float pa, pb;
        matvecPart(y_s, pa, pb);
        part[w * 128 + l] = pa;
        part[w * 128 + 64 + l] = pb;
        __syncthreads();
        float u = 0.0f;
        if (tid < M)
            u = part[tid] + part[128 + tid] + part[256 + tid] + part[384 + tid];
        float L2 = blockReduce(tid < M ? u * u : 0.0f);
        float Lv = sqrtf(L2);
        step = 1.0f / fmaxf(Lv, 1e-12f);
    }

    // ---- Phase 3: FISTA ----
    if (tid < M) { lam_s[tid] = 0.0f; y_s[tid] = 0.0f; }
    float tk = 1.0f;
    __syncthreads();
    for (int it = 0; it < NITER; ++it) {
        float pa, pb;
        matvecPart(y_s, pa, pb);
        part[w * 128 + l] = pa;
        part[w * 128 + 64 + l] = pb;
        __syncthreads();
        float tkn = 0.5f * (1.0f + sqrtf(1.0f + 4.0f * tk * tk));
        if (tid < M) {
            float g = part[tid] + part[128 + tid] + part[256 + tid] + part[384 + tid]
                    - b_s[tid];
            float ln = fmaxf(y_s[tid] - step * g, 0.0f);
            float yn = ln + ((tk - 1.0f) / tkn) * (ln - lam_s[tid]);
            lam_s[tid] = ln;
            y_s[tid] = yn;
        }
        tk = tkn;
        __syncthreads();
    }

    // ---- Phase 4: cosine via lam^T b, lam^T G lam, ||p|| ----
    {
        float pa, pb;
        matvecPart(lam_s, pa, pb);
        part[w * 128 + l] = pa;
        part[w * 128 + 64 + l] = pb;
        __syncthreads();
        float s1 = 0.0f, s2 = 0.0f;
        if (tid < M) {
            float u = part[tid] + part[128 + tid] + part[256 + tid] + part[384 + tid];
            s1 = lam_s[tid] * u;          // lam^T G lam = ||proj||^2
            s2 = lam_s[tid] * b_s[tid];   // lam^T b    = p . proj
        }
        float glg = blockReduce(s1);
        float lb  = blockReduce(s2);
        if (tid == 0) {
            float np_ = sqrtf(fmaxf(glg, 0.0f));
            float pdot = lb / (np_ + 1e-12f);                    // p . proj_normalized
            float qn = fmaxf(np_ / (np_ + 1e-12f), 1e-8f);       // ||proj_normalized||
            float pn = fmaxf(sqrtf(pn2), 1e-8f);
            float c = pdot / (pn * qn);
            atomicAdd(out, -c * (1.0f / (float)BATCH));
        }
    }
}

extern "C" void kernel_launch(void* const* d_in, const int* in_sizes, int n_in,
                              void* d_out, int out_size, void* d_ws, size_t ws_size,
                              hipStream_t stream) {
    const float* pred = (const float*)d_in[0];  // (512, 512)
    const float* ctr  = (const float*)d_in[1];  // (512, 128, 512)
    float* out = (float*)d_out;                 // scalar
    hipMemsetAsync(out, 0, sizeof(float), stream);
    nnls_cone_kernel<<<BATCH, 256, 0, stream>>>(pred, ctr, out);
}